// Round 8
// baseline (513.551 us; speedup 1.0000x reference)
//
#include <hip/hip_runtime.h>
#include <hip/hip_bf16.h>

#define LL 512
#define CC 128
#define MM (LL*LL)   // 262144 positions

typedef __attribute__((ext_vector_type(8))) short bf16x8;
typedef __attribute__((ext_vector_type(4))) float f32x4;
using bf16 = __hip_bfloat16;

__device__ __forceinline__ unsigned short f2bfbits(float f) {
    bf16 h = __float2bfloat16(f);
    return *reinterpret_cast<unsigned short*>(&h);
}
__device__ __forceinline__ float bfbits2f(unsigned short b) {
    union { unsigned int u; float f; } cv; cv.u = ((unsigned int)b) << 16; return cv.f;
}
__device__ __forceinline__ void storeT(float* p, float v) { *p = v; }
__device__ __forceinline__ void storeT(bf16* p, float v) { *p = __float2bfloat16(v); }
__device__ __forceinline__ float4 load4(const float* p) { return *(const float4*)p; }
__device__ __forceinline__ float4 load4(const bf16* p) {
    ushort4 u = *(const ushort4*)p;
    float4 f;
    f.x = bfbits2f(u.x); f.y = bfbits2f(u.y);
    f.z = bfbits2f(u.z); f.w = bfbits2f(u.w);
    return f;
}

// load 8 consecutive fp32 and convert to a bf16x8 fragment (in-register
// weight conversion; same RNE rounding as __float2bfloat16 — bit-identical).
__device__ __forceinline__ bf16x8 load8_cvt(const float* p) {
    float4 f0 = *(const float4*)p;
    float4 f1 = *(const float4*)(p + 4);
    union { bf16x8 v; unsigned short u[8]; } r;
    r.u[0] = f2bfbits(f0.x); r.u[1] = f2bfbits(f0.y);
    r.u[2] = f2bfbits(f0.z); r.u[3] = f2bfbits(f0.w);
    r.u[4] = f2bfbits(f1.x); r.u[5] = f2bfbits(f1.y);
    r.u[6] = f2bfbits(f1.z); r.u[7] = f2bfbits(f1.w);
    return r.v;
}

// sigmoid-gate: v * sigmoid(g), with v_rcp_f32 instead of the ~10-instr
// IEEE divide sequence (rcp ~1ulp; downstream rounds to bf16/fp32 — safe).
__device__ __forceinline__ float sig_gate(float g, float v) {
    return v * __builtin_amdgcn_rcpf(1.f + __expf(-g));
}

// raw fp32x8 prefetch holder: issue loads early, convert at use
struct Raw8F {
    float4 a, b;
    __device__ __forceinline__ void load(const float* p) {
        a = *(const float4*)p; b = *(const float4*)(p + 4);
    }
};
__device__ __forceinline__ bf16x8 raw2bf(const Raw8F& r) {
    union { bf16x8 v; unsigned short u[8]; } o;
    o.u[0] = f2bfbits(r.a.x); o.u[1] = f2bfbits(r.a.y);
    o.u[2] = f2bfbits(r.a.z); o.u[3] = f2bfbits(r.a.w);
    o.u[4] = f2bfbits(r.b.x); o.u[5] = f2bfbits(r.b.y);
    o.u[6] = f2bfbits(r.b.z); o.u[7] = f2bfbits(r.b.w);
    return o.v;
}

// ---------------------------------------------------------------------------
// K1: FUSED dual-sided projection — R11 BARRIER-FREE rewrite.
// 512 threads = 8 waves; waves 0-3 left, 4-7 right; x read once per block.
// Rationale: the LDS-staged version had ONE 8-wave block/CU (156+ regs ->
// 3 waves/SIMD) and 8 __syncthreads per block — every barrier idled the
// whole CU (all pipes <24%). The 16x16x32 A-frag layout is row-per-lane:
// lane (lrow,lq) needs 8 contiguous fp32 of row mt*16+lrow at col kk*32+
// lq*8 — so each wave loads A-frags DIRECTLY from global x (2x float4) and
// converts in-register. No LDS, no barriers; waves self-pace. The 8 waves
// re-read the same 32KB x-tile through the CU's shared L1 (HBM FETCH
// stays 1x); redundant cvt is ~1us chip-wide. 1-kk-deep register prefetch
// ping-pong (raw[2][4], statically indexed after full unroll).
// Numerics bit-identical (same RNE cvt, same MFMA order).
// Guards: FETCH <=85MB, WRITE ~131MB, LDS=0.
// ---------------------------------------------------------------------------
__global__ __launch_bounds__(512, 2) void proj_lr_kernel(
    const float* __restrict__ X,
    const float* __restrict__ Wl1, const float* __restrict__ Bl1,
    const float* __restrict__ Wl2, const float* __restrict__ Bl2,
    const float* __restrict__ Wr1, const float* __restrict__ Br1,
    const float* __restrict__ Wr2, const float* __restrict__ Br2,
    bf16* __restrict__ OUTL, bf16* __restrict__ OUTR)
{
    const int t = threadIdx.x;
    const int wave = t >> 6, lane = t & 63;
    const int grp = wave >> 2;            // 0 = left, 1 = right
    const int w4 = wave & 3;
    const int lrow = lane & 15, lq = lane >> 4;
    const int n0 = w4 * 32 + lrow;

    const float* W1 = grp ? Wr1 : Wl1;
    const float* W2 = grp ? Wr2 : Wl2;
    const float* B1 = grp ? Br1 : Bl1;
    const float* B2 = grp ? Br2 : Bl2;
    bf16* OUT = grp ? OUTR : OUTL;

    // W fragments + biases, register-resident for the whole block
    bf16x8 wf1[2][4], wf2[2][4];          // [nt_local][k0/32]
    float bias1[2], bias2[2];
    #pragma unroll
    for (int nl = 0; nl < 2; ++nl) {
        const int n = n0 + nl * 16;
        bias1[nl] = B1[n]; bias2[nl] = B2[n];
        #pragma unroll
        for (int kk = 0; kk < 4; ++kk) {
            wf1[nl][kk] = load8_cvt(W1 + n * CC + kk * 32 + lq * 8);
            wf2[nl][kk] = load8_cvt(W2 + n * CC + kk * 32 + lq * 8);
        }
    }

    constexpr int T = 4;
    const size_t block_row0 = (size_t)blockIdx.x * (64 * T);
    // per-lane x base: row (block_row0 + lrow), col lq*8
    const float* Xl = X + (block_row0 + lrow) * CC + lq * 8;

    // prologue: issue tile0/kk0 A-frag loads
    Raw8F raw[2][4];
    #pragma unroll
    for (int mt = 0; mt < 4; ++mt)
        raw[0][mt].load(Xl + (mt * 16) * CC);

    #pragma unroll
    for (int tt = 0; tt < T; ++tt) {
        const size_t row0 = block_row0 + (size_t)tt * 64;

        f32x4 acc1[2][4], acc2[2][4];     // [nt_local][mt]
        const f32x4 z = {0.f, 0.f, 0.f, 0.f};
        #pragma unroll
        for (int nl = 0; nl < 2; ++nl)
            #pragma unroll
            for (int mt = 0; mt < 4; ++mt) { acc1[nl][mt] = z; acc2[nl][mt] = z; }

        #pragma unroll
        for (int kk = 0; kk < 4; ++kk) {
            const int c = kk & 1, nx = c ^ 1;
            // issue next k-slice (or next tile's kk0) while this one computes
            if (kk < 3) {
                #pragma unroll
                for (int mt = 0; mt < 4; ++mt)
                    raw[nx][mt].load(Xl + (tt * 64 + mt * 16) * CC + (kk + 1) * 32);
            } else if (tt + 1 < T) {
                #pragma unroll
                for (int mt = 0; mt < 4; ++mt)
                    raw[nx][mt].load(Xl + ((tt + 1) * 64 + mt * 16) * CC);
            }

            bf16x8 a[4];
            #pragma unroll
            for (int mt = 0; mt < 4; ++mt)
                a[mt] = raw2bf(raw[c][mt]);   // waitcnt + cvt land here
            #pragma unroll
            for (int nl = 0; nl < 2; ++nl)
                #pragma unroll
                for (int mt = 0; mt < 4; ++mt) {
                    acc1[nl][mt] = __builtin_amdgcn_mfma_f32_16x16x32_bf16(
                        a[mt], wf1[nl][kk], acc1[nl][mt], 0, 0, 0);
                    acc2[nl][mt] = __builtin_amdgcn_mfma_f32_16x16x32_bf16(
                        a[mt], wf2[nl][kk], acc2[nl][mt], 0, 0, 0);
                }
        }

        // epilogue: transposed bf16 store. C/D: col=lane&15 (n), row=lq*4+reg (m)
        // (next tile's kk0 loads are already in flight above this)
        #pragma unroll
        for (int nl = 0; nl < 2; ++nl) {
            const int n = n0 + nl * 16;
            #pragma unroll
            for (int mt = 0; mt < 4; ++mt) {
                const size_t m0 = row0 + mt * 16 + lq * 4;
                union { ushort4 v; unsigned short u[4]; } pk;
                #pragma unroll
                for (int r = 0; r < 4; ++r) {
                    float p1 = acc1[nl][mt][r] + bias1[nl];
                    float p2 = acc2[nl][mt][r] + bias2[nl];
                    pk.u[r] = f2bfbits(sig_gate(p1, p2));
                }
                *(ushort4*)(OUT + (size_t)n * MM + m0) = pk.v;
            }
        }
    }
}

// ---------------------------------------------------------------------------
// K2: per-channel batched GEMM  tri[c] = L_c (512x512) @ R_c^T (512x512)
// LOCKED round-0 structure — 95-99us, FETCH ~200MB, WRITE=ideal, VGPR 88,
// occupancy ~18% (proven rounds 0/2/5). DO NOT MODIFY the loop/grid:
// three pipelining attempts failed via (a) XCD-swizzle write concentration
// (R4: WRITE 3x), (b) 1-barrier desync read-reuse decay (R6: FETCH +45MB),
// (c) reg-prefetch occupancy rise -> L2 thrash (R7: WRITE 4x). The
// 2-barrier lockstep at ~5 blocks/CU IS the L2 locality mechanism.
// bf16 output (R9, verified: absmax unchanged at 0.03125).
// ---------------------------------------------------------------------------
template<typename TriT>
__global__ __launch_bounds__(256) void tri_mm_kernel(
    const bf16* __restrict__ Lt, const bf16* __restrict__ Rt,
    TriT* __restrict__ tri)
{
    __shared__ bf16 As[128][40];          // +8 bf16 pad: 80B row stride
    __shared__ bf16 Bs[128][40];
    const int c  = blockIdx.z;
    const int i0 = blockIdx.x * 128, j0 = blockIdx.y * 128;
    const bf16* Lb = Lt + (size_t)c * MM;
    const bf16* Rb = Rt + (size_t)c * MM;

    const int t    = threadIdx.x;
    const int wave = t >> 6, lane = t & 63;
    const int lrow = lane & 15, lq = lane >> 4;
    const int wi = (wave & 1) * 64, wj = (wave >> 1) * 64;

    f32x4 acc[4][4];
    const f32x4 z = {0.f, 0.f, 0.f, 0.f};
    #pragma unroll
    for (int mt = 0; mt < 4; ++mt)
        #pragma unroll
        for (int nt = 0; nt < 4; ++nt) acc[mt][nt] = z;

    for (int k0 = 0; k0 < LL; k0 += 32) {
        __syncthreads();
        #pragma unroll
        for (int it = 0; it < 2; ++it) {
            int chunk = it * 256 + t;
            int r = chunk >> 2, o = (chunk & 3) << 3;
            *(uint4*)(&As[r][o]) = *(const uint4*)(Lb + (size_t)(i0 + r) * LL + k0 + o);
            *(uint4*)(&Bs[r][o]) = *(const uint4*)(Rb + (size_t)(j0 + r) * LL + k0 + o);
        }
        __syncthreads();

        bf16x8 af[4], bfr[4];
        #pragma unroll
        for (int mt = 0; mt < 4; ++mt)
            af[mt] = *(const bf16x8*)(&As[wi + mt * 16 + lrow][lq * 8]);
        #pragma unroll
        for (int nt = 0; nt < 4; ++nt)
            bfr[nt] = *(const bf16x8*)(&Bs[wj + nt * 16 + lrow][lq * 8]);
        #pragma unroll
        for (int mt = 0; mt < 4; ++mt)
            #pragma unroll
            for (int nt = 0; nt < 4; ++nt)
                acc[mt][nt] = __builtin_amdgcn_mfma_f32_16x16x32_bf16(
                    af[mt], bfr[nt], acc[mt][nt], 0, 0, 0);
    }

    TriT* triC = tri + (size_t)c * MM;
    #pragma unroll
    for (int mt = 0; mt < 4; ++mt) {
        #pragma unroll
        for (int nt = 0; nt < 4; ++nt) {
            const int ib = i0 + wi + mt * 16 + lq * 4;
            const int j  = j0 + wj + nt * 16 + lrow;
            #pragma unroll
            for (int r = 0; r < 4; ++r)
                storeT(&triC[(size_t)(ib + r) * LL + j], acc[mt][nt][r]);
        }
    }
}

// ---------------------------------------------------------------------------
// K3: FUSED LayerNorm + output gating. (R6 structure; bf16 tri read;
// fp32 W with in-register cvt.)
// ---------------------------------------------------------------------------
template<typename TriT>
__global__ __launch_bounds__(256, 2) void ln_gate_kernel(
    const TriT* __restrict__ tri,
    const float* __restrict__ G, const float* __restrict__ Bt,
    const float* __restrict__ W1, const float* __restrict__ B1,
    const float* __restrict__ W2, const float* __restrict__ B2,
    float* __restrict__ OUT)
{
    __shared__ float s[128][68];          // tri tile [c][p], 272B row stride
    __shared__ bf16 xs[64][136];          // normalized bf16 tile [p][c]
    __shared__ float part[2][4][64];
    __shared__ float mu[64], rsd[64];
    __shared__ float gs[128], bs[128];

    const int t = threadIdx.x;
    const int wave = t >> 6, lane = t & 63;
    const int lrow = lane & 15, lq = lane >> 4;
    const int n0 = wave * 32 + lrow;

    if (t < 128) { gs[t] = G[t]; bs[t] = Bt[t]; }

    bf16x8 wf1[2][4], wf2[2][4];
    float bias1[2], bias2[2];
    #pragma unroll
    for (int nl = 0; nl < 2; ++nl) {
        const int n = n0 + nl * 16;
        bias1[nl] = B1[n]; bias2[nl] = B2[n];
        #pragma unroll
        for (int kk = 0; kk < 4; ++kk) {
            wf1[nl][kk] = load8_cvt(W1 + n * CC + kk * 32 + lq * 8);
            wf2[nl][kk] = load8_cvt(W2 + n * CC + kk * 32 + lq * 8);
        }
    }

    constexpr int T = 4;
    const size_t bp0 = (size_t)blockIdx.x * (64 * T);

    // prologue: stage tri tile 0 (128c x 64p -> s)
    #pragma unroll
    for (int it = 0; it < 8; ++it) {
        int idx = it * 256 + t;
        int cc = idx >> 4, p4 = (idx & 15) << 2;
        float4 f = load4(tri + (size_t)cc * MM + bp0 + p4);
        *(float4*)(&s[cc][p4]) = f;
    }

    for (int tt = 0; tt < T; ++tt) {
        const size_t p0 = bp0 + (size_t)tt * 64;

        float4 pf[8];
        if (tt + 1 < T) {
            #pragma unroll
            for (int it = 0; it < 8; ++it) {
                int idx = it * 256 + t;
                int cc = idx >> 4, p4 = (idx & 15) << 2;
                pf[it] = load4(tri + (size_t)cc * MM + p0 + 64 + p4);
            }
        }
        __syncthreads();   // (a) s staged (prologue or prev commit); gs/bs ready

        // LN stats: wave w sums channels [w*32, w*32+32) at position=lane
        float sum = 0.f, sq = 0.f;
        #pragma unroll 8
        for (int cc = wave * 32; cc < wave * 32 + 32; ++cc) {
            float v = s[cc][lane]; sum += v; sq += v * v;
        }
        part[0][wave][lane] = sum; part[1][wave][lane] = sq;
        __syncthreads();   // (b)
        if (t < 64) {
            float S = part[0][0][t] + part[0][1][t] + part[0][2][t] + part[0][3][t];
            float Q = part[1][0][t] + part[1][1][t] + part[1][2][t] + part[1][3][t];
            float m = S * (1.f / 128.f);
            float var = Q * (1.f / 128.f) - m * m;
            mu[t] = m; rsd[t] = rsqrtf(var + 1e-5f);
        }
        __syncthreads();   // (c)

        // normalize -> xs bf16. p = lane (conflict-free s reads), c8 uniform.
        #pragma unroll
        for (int it = 0; it < 4; ++it) {
            int chunk = it * 256 + t;
            int p = chunk & 63, c8 = (chunk >> 6) << 3;
            float m = mu[p], r = rsd[p];
            union { uint4 v; unsigned short u[8]; } pk;
            #pragma unroll
            for (int jj = 0; jj < 8; ++jj) {
                int cc = c8 + jj;
                pk.u[jj] = f2bfbits((s[cc][p] - m) * r * gs[cc] + bs[cc]);
            }
            *(uint4*)(&xs[p][c8]) = pk.v;
        }
        __syncthreads();   // (d) xs ready; all s reads done

        if (tt + 1 < T) {
            #pragma unroll
            for (int it = 0; it < 8; ++it) {
                int idx = it * 256 + t;
                int cc = idx >> 4, p4 = (idx & 15) << 2;
                *(float4*)(&s[cc][p4]) = pf[it];
            }
        }

        f32x4 acc1[2][4], acc2[2][4];
        const f32x4 z = {0.f, 0.f, 0.f, 0.f};
        #pragma unroll
        for (int nl = 0; nl < 2; ++nl)
            #pragma unroll
            for (int mt = 0; mt < 4; ++mt) { acc1[nl][mt] = z; acc2[nl][mt] = z; }

        #pragma unroll
        for (int kk = 0; kk < 4; ++kk) {
            bf16x8 a[4];
            #pragma unroll
            for (int mt = 0; mt < 4; ++mt)
                a[mt] = *(const bf16x8*)(&xs[mt * 16 + lrow][kk * 32 + lq * 8]);
            #pragma unroll
            for (int nl = 0; nl < 2; ++nl)
                #pragma unroll
                for (int mt = 0; mt < 4; ++mt) {
                    acc1[nl][mt] = __builtin_amdgcn_mfma_f32_16x16x32_bf16(
                        a[mt], wf1[nl][kk], acc1[nl][mt], 0, 0, 0);
                    acc2[nl][mt] = __builtin_amdgcn_mfma_f32_16x16x32_bf16(
                        a[mt], wf2[nl][kk], acc2[nl][mt], 0, 0, 0);
                }
        }

        // epilogue: fp32 out [M][128]
        #pragma unroll
        for (int nl = 0; nl < 2; ++nl) {
            const int n = n0 + nl * 16;
            #pragma unroll
            for (int mt = 0; mt < 4; ++mt) {
                const size_t m0 = p0 + mt * 16 + lq * 4;
                #pragma unroll
                for (int r = 0; r < 4; ++r) {
                    float p1 = acc1[nl][mt][r] + bias1[nl];
                    float p2 = acc2[nl][mt][r] + bias2[nl];
                    OUT[(m0 + r) * CC + n] = sig_gate(p1, p2);
                }
            }
        }
    }
}

// ---------------------------------------------------------------------------
extern "C" void kernel_launch(void* const* d_in, const int* in_sizes, int n_in,
                              void* d_out, int out_size, void* d_ws, size_t ws_size,
                              hipStream_t stream)
{
    const float* x   = (const float*)d_in[0];
    const float* Wl1 = (const float*)d_in[1];
    const float* bl1 = (const float*)d_in[2];
    const float* Wl2 = (const float*)d_in[3];
    const float* bl2 = (const float*)d_in[4];
    const float* Wr1 = (const float*)d_in[5];
    const float* br1 = (const float*)d_in[6];
    const float* Wr2 = (const float*)d_in[7];
    const float* br2 = (const float*)d_in[8];
    const float* Wg  = (const float*)d_in[9];
    const float* bg  = (const float*)d_in[10];
    const float* Wo  = (const float*)d_in[11];
    const float* bo  = (const float*)d_in[12];
    const float* lng = (const float*)d_in[13];
    const float* lnb = (const float*)d_in[14];
    float* out = (float*)d_out;

    char* ws = (char*)d_ws;
    bf16* left_t  = (bf16*)(ws);                        // 64 MiB bf16 [128][M]
    bf16* right_t = (bf16*)(ws + (64ull << 20));        // 64 MiB bf16 [128][M]
    bf16* tri     = (bf16*)(ws + (132ull << 20));       // 64 MiB bf16 [128][M]

    proj_lr_kernel<<<dim3(MM / 256), dim3(512), 0, stream>>>(
        x, Wl1, bl1, Wl2, bl2, Wr1, br1, Wr2, br2, left_t, right_t);
    tri_mm_kernel<bf16><<<dim3(4, 4, 128), dim3(256), 0, stream>>>(left_t, right_t, tri);
    ln_gate_kernel<bf16><<<dim3(MM / 256), dim3(256), 0, stream>>>(
        tri, lng, lnb, Wg, bg, Wo, bo, out);
}

// Round 9
// 422.706 us; speedup vs baseline: 1.2149x; 1.2149x over previous
//
#include <hip/hip_runtime.h>
#include <hip/hip_bf16.h>

#define LL 512
#define CC 128
#define MM (LL*LL)   // 262144 positions

typedef __attribute__((ext_vector_type(8))) short bf16x8;
typedef __attribute__((ext_vector_type(4))) float f32x4;
using bf16 = __hip_bfloat16;

__device__ __forceinline__ unsigned short f2bfbits(float f) {
    bf16 h = __float2bfloat16(f);
    return *reinterpret_cast<unsigned short*>(&h);
}
__device__ __forceinline__ float bfbits2f(unsigned short b) {
    union { unsigned int u; float f; } cv; cv.u = ((unsigned int)b) << 16; return cv.f;
}
__device__ __forceinline__ void storeT(float* p, float v) { *p = v; }
__device__ __forceinline__ void storeT(bf16* p, float v) { *p = __float2bfloat16(v); }
__device__ __forceinline__ float4 load4(const float* p) { return *(const float4*)p; }
__device__ __forceinline__ float4 load4(const bf16* p) {
    ushort4 u = *(const ushort4*)p;
    float4 f;
    f.x = bfbits2f(u.x); f.y = bfbits2f(u.y);
    f.z = bfbits2f(u.z); f.w = bfbits2f(u.w);
    return f;
}

// sigmoid-gate: v * sigmoid(g), with v_rcp_f32 instead of the ~10-instr
// IEEE divide sequence (rcp ~1ulp; downstream rounds to bf16/fp32 — safe).
__device__ __forceinline__ float sig_gate(float g, float v) {
    return v * __builtin_amdgcn_rcpf(1.f + __expf(-g));
}

// stage 8 consecutive fp32 elements into bf16 LDS (16B dst)
__device__ __forceinline__ void stage8(const float* src, bf16* dst) {
    float4 f0 = *(const float4*)(src);
    float4 f1 = *(const float4*)(src + 4);
    union { ushort4 v; unsigned short u[4]; } a, b;
    a.u[0] = f2bfbits(f0.x); a.u[1] = f2bfbits(f0.y);
    a.u[2] = f2bfbits(f0.z); a.u[3] = f2bfbits(f0.w);
    b.u[0] = f2bfbits(f1.x); b.u[1] = f2bfbits(f1.y);
    b.u[2] = f2bfbits(f1.z); b.u[3] = f2bfbits(f1.w);
    *(ushort4*)(dst)     = a.v;
    *(ushort4*)(dst + 4) = b.v;
}

// raw prefetch holder: load global fp32 early, convert/commit to LDS late
struct Raw8F {
    float4 a, b;
    __device__ __forceinline__ void load(const float* p) {
        a = *(const float4*)p; b = *(const float4*)(p + 4);
    }
    __device__ __forceinline__ void commit(bf16* d) const {
        union { ushort4 v; unsigned short u[4]; } x, y;
        x.u[0] = f2bfbits(a.x); x.u[1] = f2bfbits(a.y);
        x.u[2] = f2bfbits(a.z); x.u[3] = f2bfbits(a.w);
        y.u[0] = f2bfbits(b.x); y.u[1] = f2bfbits(b.y);
        y.u[2] = f2bfbits(b.z); y.u[3] = f2bfbits(b.w);
        *(ushort4*)(d)     = x.v;
        *(ushort4*)(d + 4) = y.v;
    }
};

// ---------------------------------------------------------------------------
// K0: convert six 128x128 fp32 weight matrices to bf16 in ws.
// (Restored in R12: proj_lr with precomputed bf16 W measured 99.6us vs 108
// with inline fp32 cvt — the +8us beats cvt_w's ~5us launch.)
// ---------------------------------------------------------------------------
__global__ __launch_bounds__(256) void cvt_w_kernel(
    const float* __restrict__ s0, const float* __restrict__ s1,
    const float* __restrict__ s2, const float* __restrict__ s3,
    const float* __restrict__ s4, const float* __restrict__ s5,
    bf16* __restrict__ dst)
{
    const float* srcs[6] = {s0, s1, s2, s3, s4, s5};
    const float* s = srcs[blockIdx.y];
    bf16* d = dst + blockIdx.y * (CC * CC);
    int i = (blockIdx.x * 256 + threadIdx.x) * 4;
    float4 f = *(const float4*)(s + i);
    union { ushort4 v; unsigned short u[4]; } p;
    p.u[0] = f2bfbits(f.x); p.u[1] = f2bfbits(f.y);
    p.u[2] = f2bfbits(f.z); p.u[3] = f2bfbits(f.w);
    *(ushort4*)(d + i) = p.v;
}

// ---------------------------------------------------------------------------
// K1: FUSED dual-sided projection (left AND right) — x read ONCE.
// EXACT R5 form (best measured: 99.6us, FETCH 68MB): 512 threads = 8 waves,
// waves 0-3 left / 4-7 right; bf16 Wb fragments; post-barrier prefetch
// issue; commit after epilogue; rcp sigmoid.
// proj_lr ledger: LDS-staged fused 99.6 (R5) / inline-cvt 108 (R7);
// 256-split 106.6 (R9); barrier-free 191 (R11: 1-deep reg ping-pong can't
// cover 200-900cy load latency at 3 waves/SIMD — LDS staging amortizes it
// over a full tile phase). DO NOT restructure; this is the local optimum.
// ---------------------------------------------------------------------------
__global__ __launch_bounds__(512, 2) void proj_lr_kernel(
    const float* __restrict__ X, const bf16* __restrict__ Wb,
    const float* __restrict__ Bl1, const float* __restrict__ Bl2,
    const float* __restrict__ Br1, const float* __restrict__ Br2,
    bf16* __restrict__ OUTL, bf16* __restrict__ OUTR)
{
    __shared__ bf16 xs[2][64][136];       // +8 bf16 pad: 272B row stride
    const int t = threadIdx.x;
    const int wave = t >> 6, lane = t & 63;
    const int grp = wave >> 2;            // 0 = left, 1 = right
    const int w4 = wave & 3;
    const int lrow = lane & 15, lq = lane >> 4;
    const int n0 = w4 * 32 + lrow;

    const bf16* W1 = Wb + (grp ? 2 * CC * CC : 0);
    const bf16* W2 = W1 + CC * CC;
    const float* B1 = grp ? Br1 : Bl1;
    const float* B2 = grp ? Br2 : Bl2;
    bf16* OUT = grp ? OUTR : OUTL;

    bf16x8 wf1[2][4], wf2[2][4];          // [nt_local][k0/32]
    float bias1[2], bias2[2];
    #pragma unroll
    for (int nl = 0; nl < 2; ++nl) {
        const int n = n0 + nl * 16;
        bias1[nl] = B1[n]; bias2[nl] = B2[n];
        #pragma unroll
        for (int kk = 0; kk < 4; ++kk) {
            wf1[nl][kk] = *(const bf16x8*)(W1 + n * CC + kk * 32 + lq * 8);
            wf2[nl][kk] = *(const bf16x8*)(W2 + n * CC + kk * 32 + lq * 8);
        }
    }

    constexpr int T = 4;
    const size_t block_row0 = (size_t)blockIdx.x * (64 * T);

    // stage tile 0 directly (8192 elements / 512 threads = 2 chunks of 8)
    #pragma unroll
    for (int it = 0; it < 2; ++it) {
        int chunk = it * 512 + t;
        int r = chunk >> 4, o = (chunk & 15) << 3;
        stage8(X + (block_row0 + r) * CC + o, &xs[0][r][o]);
    }

    #pragma unroll
    for (int tt = 0; tt < T; ++tt) {
        const size_t row0 = block_row0 + (size_t)tt * 64;
        const int cur = tt & 1;

        __syncthreads();   // xs[cur] staged; xs[cur^1] readers done

        // issue next tile's loads AFTER the barrier: they stay in flight
        // through MFMA + epilogue; vmcnt wait lands at commit() below.
        Raw8F pf[2];
        if (tt + 1 < T) {
            #pragma unroll
            for (int it = 0; it < 2; ++it) {
                int chunk = it * 512 + t;
                int r = chunk >> 4, o = (chunk & 15) << 3;
                pf[it].load(X + (row0 + 64 + r) * CC + o);
            }
        }

        f32x4 acc1[2][4], acc2[2][4];     // [nt_local][mt]
        const f32x4 z = {0.f, 0.f, 0.f, 0.f};
        #pragma unroll
        for (int nl = 0; nl < 2; ++nl)
            #pragma unroll
            for (int mt = 0; mt < 4; ++mt) { acc1[nl][mt] = z; acc2[nl][mt] = z; }

        #pragma unroll
        for (int kk = 0; kk < 4; ++kk) {
            bf16x8 a[4];
            #pragma unroll
            for (int mt = 0; mt < 4; ++mt)
                a[mt] = *(const bf16x8*)(&xs[cur][mt * 16 + lrow][kk * 32 + lq * 8]);
            #pragma unroll
            for (int nl = 0; nl < 2; ++nl)
                #pragma unroll
                for (int mt = 0; mt < 4; ++mt) {
                    acc1[nl][mt] = __builtin_amdgcn_mfma_f32_16x16x32_bf16(
                        a[mt], wf1[nl][kk], acc1[nl][mt], 0, 0, 0);
                    acc2[nl][mt] = __builtin_amdgcn_mfma_f32_16x16x32_bf16(
                        a[mt], wf2[nl][kk], acc2[nl][mt], 0, 0, 0);
                }
        }

        // epilogue: transposed bf16 store. C/D: col=lane&15 (n), row=lq*4+reg (m)
        #pragma unroll
        for (int nl = 0; nl < 2; ++nl) {
            const int n = n0 + nl * 16;
            #pragma unroll
            for (int mt = 0; mt < 4; ++mt) {
                const size_t m0 = row0 + mt * 16 + lq * 4;
                union { ushort4 v; unsigned short u[4]; } pk;
                #pragma unroll
                for (int r = 0; r < 4; ++r) {
                    float p1 = acc1[nl][mt][r] + bias1[nl];
                    float p2 = acc2[nl][mt][r] + bias2[nl];
                    pk.u[r] = f2bfbits(sig_gate(p1, p2));
                }
                *(ushort4*)(OUT + (size_t)n * MM + m0) = pk.v;
            }
        }

        // commit prefetched tile LAST: maximizes load-latency cover.
        if (tt + 1 < T) {
            #pragma unroll
            for (int it = 0; it < 2; ++it) {
                int chunk = it * 512 + t;
                int r = chunk >> 4, o = (chunk & 15) << 3;
                pf[it].commit(&xs[cur ^ 1][r][o]);
            }
        }
    }
}

// ---------------------------------------------------------------------------
// K2: per-channel batched GEMM  tri[c] = L_c (512x512) @ R_c^T (512x512)
// LOCKED round-0 structure — 90-99us, FETCH ~200MB, WRITE=ideal, VGPR 88,
// occupancy ~18% (proven rounds 0/2/5/6/7). DO NOT MODIFY the loop/grid:
// three pipelining attempts failed via (a) XCD-swizzle write concentration
// (R4: WRITE 3x), (b) 1-barrier desync read-reuse decay (R6: FETCH +45MB),
// (c) reg-prefetch occupancy rise -> L2 thrash (R7: WRITE 4x). The
// 2-barrier lockstep at ~5 blocks/CU IS the L2 locality mechanism.
// bf16 output (R9, verified: absmax unchanged at 0.03125).
// ---------------------------------------------------------------------------
template<typename TriT>
__global__ __launch_bounds__(256) void tri_mm_kernel(
    const bf16* __restrict__ Lt, const bf16* __restrict__ Rt,
    TriT* __restrict__ tri)
{
    __shared__ bf16 As[128][40];          // +8 bf16 pad: 80B row stride
    __shared__ bf16 Bs[128][40];
    const int c  = blockIdx.z;
    const int i0 = blockIdx.x * 128, j0 = blockIdx.y * 128;
    const bf16* Lb = Lt + (size_t)c * MM;
    const bf16* Rb = Rt + (size_t)c * MM;

    const int t    = threadIdx.x;
    const int wave = t >> 6, lane = t & 63;
    const int lrow = lane & 15, lq = lane >> 4;
    const int wi = (wave & 1) * 64, wj = (wave >> 1) * 64;

    f32x4 acc[4][4];
    const f32x4 z = {0.f, 0.f, 0.f, 0.f};
    #pragma unroll
    for (int mt = 0; mt < 4; ++mt)
        #pragma unroll
        for (int nt = 0; nt < 4; ++nt) acc[mt][nt] = z;

    for (int k0 = 0; k0 < LL; k0 += 32) {
        __syncthreads();
        #pragma unroll
        for (int it = 0; it < 2; ++it) {
            int chunk = it * 256 + t;
            int r = chunk >> 2, o = (chunk & 3) << 3;
            *(uint4*)(&As[r][o]) = *(const uint4*)(Lb + (size_t)(i0 + r) * LL + k0 + o);
            *(uint4*)(&Bs[r][o]) = *(const uint4*)(Rb + (size_t)(j0 + r) * LL + k0 + o);
        }
        __syncthreads();

        bf16x8 af[4], bfr[4];
        #pragma unroll
        for (int mt = 0; mt < 4; ++mt)
            af[mt] = *(const bf16x8*)(&As[wi + mt * 16 + lrow][lq * 8]);
        #pragma unroll
        for (int nt = 0; nt < 4; ++nt)
            bfr[nt] = *(const bf16x8*)(&Bs[wj + nt * 16 + lrow][lq * 8]);
        #pragma unroll
        for (int mt = 0; mt < 4; ++mt)
            #pragma unroll
            for (int nt = 0; nt < 4; ++nt)
                acc[mt][nt] = __builtin_amdgcn_mfma_f32_16x16x32_bf16(
                    af[mt], bfr[nt], acc[mt][nt], 0, 0, 0);
    }

    TriT* triC = tri + (size_t)c * MM;
    #pragma unroll
    for (int mt = 0; mt < 4; ++mt) {
        #pragma unroll
        for (int nt = 0; nt < 4; ++nt) {
            const int ib = i0 + wi + mt * 16 + lq * 4;
            const int j  = j0 + wj + nt * 16 + lrow;
            #pragma unroll
            for (int r = 0; r < 4; ++r)
                storeT(&triC[(size_t)(ib + r) * LL + j], acc[mt][nt][r]);
        }
    }
}

// ---------------------------------------------------------------------------
// K3: FUSED LayerNorm + output gating. (R6 structure; bf16 tri read;
// bf16 Wb weights — rounds 5/6 proven <=~85us.)
// ---------------------------------------------------------------------------
template<typename TriT>
__global__ __launch_bounds__(256, 2) void ln_gate_kernel(
    const TriT* __restrict__ tri,
    const float* __restrict__ G, const float* __restrict__ Bt,
    const bf16* __restrict__ W1, const float* __restrict__ B1,
    const bf16* __restrict__ W2, const float* __restrict__ B2,
    float* __restrict__ OUT)
{
    __shared__ float s[128][68];          // tri tile [c][p], 272B row stride
    __shared__ bf16 xs[64][136];          // normalized bf16 tile [p][c]
    __shared__ float part[2][4][64];
    __shared__ float mu[64], rsd[64];
    __shared__ float gs[128], bs[128];

    const int t = threadIdx.x;
    const int wave = t >> 6, lane = t & 63;
    const int lrow = lane & 15, lq = lane >> 4;
    const int n0 = wave * 32 + lrow;

    if (t < 128) { gs[t] = G[t]; bs[t] = Bt[t]; }

    bf16x8 wf1[2][4], wf2[2][4];
    float bias1[2], bias2[2];
    #pragma unroll
    for (int nl = 0; nl < 2; ++nl) {
        const int n = n0 + nl * 16;
        bias1[nl] = B1[n]; bias2[nl] = B2[n];
        #pragma unroll
        for (int kk = 0; kk < 4; ++kk) {
            wf1[nl][kk] = *(const bf16x8*)(W1 + n * CC + kk * 32 + lq * 8);
            wf2[nl][kk] = *(const bf16x8*)(W2 + n * CC + kk * 32 + lq * 8);
        }
    }

    constexpr int T = 4;
    const size_t bp0 = (size_t)blockIdx.x * (64 * T);

    // prologue: stage tri tile 0 (128c x 64p -> s)
    #pragma unroll
    for (int it = 0; it < 8; ++it) {
        int idx = it * 256 + t;
        int cc = idx >> 4, p4 = (idx & 15) << 2;
        float4 f = load4(tri + (size_t)cc * MM + bp0 + p4);
        *(float4*)(&s[cc][p4]) = f;
    }

    for (int tt = 0; tt < T; ++tt) {
        const size_t p0 = bp0 + (size_t)tt * 64;

        float4 pf[8];
        if (tt + 1 < T) {
            #pragma unroll
            for (int it = 0; it < 8; ++it) {
                int idx = it * 256 + t;
                int cc = idx >> 4, p4 = (idx & 15) << 2;
                pf[it] = load4(tri + (size_t)cc * MM + p0 + 64 + p4);
            }
        }
        __syncthreads();   // (a) s staged (prologue or prev commit); gs/bs ready

        // LN stats: wave w sums channels [w*32, w*32+32) at position=lane
        float sum = 0.f, sq = 0.f;
        #pragma unroll 8
        for (int cc = wave * 32; cc < wave * 32 + 32; ++cc) {
            float v = s[cc][lane]; sum += v; sq += v * v;
        }
        part[0][wave][lane] = sum; part[1][wave][lane] = sq;
        __syncthreads();   // (b)
        if (t < 64) {
            float S = part[0][0][t] + part[0][1][t] + part[0][2][t] + part[0][3][t];
            float Q = part[1][0][t] + part[1][1][t] + part[1][2][t] + part[1][3][t];
            float m = S * (1.f / 128.f);
            float var = Q * (1.f / 128.f) - m * m;
            mu[t] = m; rsd[t] = rsqrtf(var + 1e-5f);
        }
        __syncthreads();   // (c)

        // normalize -> xs bf16. p = lane (conflict-free s reads), c8 uniform.
        #pragma unroll
        for (int it = 0; it < 4; ++it) {
            int chunk = it * 256 + t;
            int p = chunk & 63, c8 = (chunk >> 6) << 3;
            float m = mu[p], r = rsd[p];
            union { uint4 v; unsigned short u[8]; } pk;
            #pragma unroll
            for (int jj = 0; jj < 8; ++jj) {
                int cc = c8 + jj;
                pk.u[jj] = f2bfbits((s[cc][p] - m) * r * gs[cc] + bs[cc]);
            }
            *(uint4*)(&xs[p][c8]) = pk.v;
        }
        __syncthreads();   // (d) xs ready; all s reads done

        if (tt + 1 < T) {
            #pragma unroll
            for (int it = 0; it < 8; ++it) {
                int idx = it * 256 + t;
                int cc = idx >> 4, p4 = (idx & 15) << 2;
                *(float4*)(&s[cc][p4]) = pf[it];
            }
        }

        f32x4 acc1[2][4], acc2[2][4];
        const f32x4 z = {0.f, 0.f, 0.f, 0.f};
        #pragma unroll
        for (int nl = 0; nl < 2; ++nl)
            #pragma unroll
            for (int mt = 0; mt < 4; ++mt) { acc1[nl][mt] = z; acc2[nl][mt] = z; }

        #pragma unroll
        for (int kk = 0; kk < 4; ++kk) {
            bf16x8 a[4];
            #pragma unroll
            for (int mt = 0; mt < 4; ++mt)
                a[mt] = *(const bf16x8*)(&xs[mt * 16 + lrow][kk * 32 + lq * 8]);
            #pragma unroll
            for (int nl = 0; nl < 2; ++nl)
                #pragma unroll
                for (int mt = 0; mt < 4; ++mt) {
                    acc1[nl][mt] = __builtin_amdgcn_mfma_f32_16x16x32_bf16(
                        a[mt], wf1[nl][kk], acc1[nl][mt], 0, 0, 0);
                    acc2[nl][mt] = __builtin_amdgcn_mfma_f32_16x16x32_bf16(
                        a[mt], wf2[nl][kk], acc2[nl][mt], 0, 0, 0);
                }
        }

        // epilogue: fp32 out [M][128]
        #pragma unroll
        for (int nl = 0; nl < 2; ++nl) {
            const int n = n0 + nl * 16;
            #pragma unroll
            for (int mt = 0; mt < 4; ++mt) {
                const size_t m0 = p0 + mt * 16 + lq * 4;
                #pragma unroll
                for (int r = 0; r < 4; ++r) {
                    float p1 = acc1[nl][mt][r] + bias1[nl];
                    float p2 = acc2[nl][mt][r] + bias2[nl];
                    OUT[(m0 + r) * CC + n] = sig_gate(p1, p2);
                }
            }
        }
    }
}

// ---------------------------------------------------------------------------
extern "C" void kernel_launch(void* const* d_in, const int* in_sizes, int n_in,
                              void* d_out, int out_size, void* d_ws, size_t ws_size,
                              hipStream_t stream)
{
    const float* x   = (const float*)d_in[0];
    const float* Wl1 = (const float*)d_in[1];
    const float* bl1 = (const float*)d_in[2];
    const float* Wl2 = (const float*)d_in[3];
    const float* bl2 = (const float*)d_in[4];
    const float* Wr1 = (const float*)d_in[5];
    const float* br1 = (const float*)d_in[6];
    const float* Wr2 = (const float*)d_in[7];
    const float* br2 = (const float*)d_in[8];
    const float* Wg  = (const float*)d_in[9];
    const float* bg  = (const float*)d_in[10];
    const float* Wo  = (const float*)d_in[11];
    const float* bo  = (const float*)d_in[12];
    const float* lng = (const float*)d_in[13];
    const float* lnb = (const float*)d_in[14];
    float* out = (float*)d_out;

    char* ws = (char*)d_ws;
    bf16* left_t  = (bf16*)(ws);                        // 64 MiB bf16 [128][M]
    bf16* right_t = (bf16*)(ws + (64ull << 20));        // 64 MiB bf16 [128][M]
    bf16* Wb      = (bf16*)(ws + (128ull << 20));       // 192 KiB: 6 bf16 weights
    bf16* tri     = (bf16*)(ws + (132ull << 20));       // 64 MiB bf16 [128][M]

    bf16* Wbg = Wb + 4 * CC * CC;
    bf16* Wbo = Wb + 5 * CC * CC;

    dim3 blk(256);
    cvt_w_kernel<<<dim3(16, 6), blk, 0, stream>>>(Wl1, Wl2, Wr1, Wr2, Wg, Wo, Wb);
    proj_lr_kernel<<<dim3(MM / 256), dim3(512), 0, stream>>>(
        x, Wb, bl1, bl2, br1, br2, left_t, right_t);
    tri_mm_kernel<bf16><<<dim3(4, 4, 128), blk, 0, stream>>>(left_t, right_t, tri);
    ln_gate_kernel<bf16><<<dim3(MM / 256), blk, 0, stream>>>(
        tri, lng, lnb, Wbg, bg, Wbo, bo, out);
}

// Round 10
// 417.579 us; speedup vs baseline: 1.2298x; 1.0123x over previous
//
#include <hip/hip_runtime.h>
#include <hip/hip_bf16.h>

#define LL 512
#define CC 128
#define MM (LL*LL)   // 262144 positions

typedef __attribute__((ext_vector_type(8))) short bf16x8;
typedef __attribute__((ext_vector_type(4))) float f32x4;
using bf16 = __hip_bfloat16;

__device__ __forceinline__ unsigned short f2bfbits(float f) {
    bf16 h = __float2bfloat16(f);
    return *reinterpret_cast<unsigned short*>(&h);
}
__device__ __forceinline__ float bfbits2f(unsigned short b) {
    union { unsigned int u; float f; } cv; cv.u = ((unsigned int)b) << 16; return cv.f;
}
__device__ __forceinline__ void storeT(float* p, float v) { *p = v; }
__device__ __forceinline__ void storeT(bf16* p, float v) { *p = __float2bfloat16(v); }
__device__ __forceinline__ float4 load4(const float* p) { return *(const float4*)p; }
__device__ __forceinline__ float4 load4(const bf16* p) {
    ushort4 u = *(const ushort4*)p;
    float4 f;
    f.x = bfbits2f(u.x); f.y = bfbits2f(u.y);
    f.z = bfbits2f(u.z); f.w = bfbits2f(u.w);
    return f;
}

// sigmoid-gate: v * sigmoid(g), with v_rcp_f32 instead of the ~10-instr
// IEEE divide sequence (rcp ~1ulp; downstream rounds to bf16/fp32 — safe).
__device__ __forceinline__ float sig_gate(float g, float v) {
    return v * __builtin_amdgcn_rcpf(1.f + __expf(-g));
}

// stage 8 consecutive fp32 elements into bf16 LDS (16B dst)
__device__ __forceinline__ void stage8(const float* src, bf16* dst) {
    float4 f0 = *(const float4*)(src);
    float4 f1 = *(const float4*)(src + 4);
    union { ushort4 v; unsigned short u[4]; } a, b;
    a.u[0] = f2bfbits(f0.x); a.u[1] = f2bfbits(f0.y);
    a.u[2] = f2bfbits(f0.z); a.u[3] = f2bfbits(f0.w);
    b.u[0] = f2bfbits(f1.x); b.u[1] = f2bfbits(f1.y);
    b.u[2] = f2bfbits(f1.z); b.u[3] = f2bfbits(f1.w);
    *(ushort4*)(dst)     = a.v;
    *(ushort4*)(dst + 4) = b.v;
}

// raw prefetch holder: load global fp32 early, convert/commit to LDS late
struct Raw8F {
    float4 a, b;
    __device__ __forceinline__ void load(const float* p) {
        a = *(const float4*)p; b = *(const float4*)(p + 4);
    }
    __device__ __forceinline__ void commit(bf16* d) const {
        union { ushort4 v; unsigned short u[4]; } x, y;
        x.u[0] = f2bfbits(a.x); x.u[1] = f2bfbits(a.y);
        x.u[2] = f2bfbits(a.z); x.u[3] = f2bfbits(a.w);
        y.u[0] = f2bfbits(b.x); y.u[1] = f2bfbits(b.y);
        y.u[2] = f2bfbits(b.z); y.u[3] = f2bfbits(b.w);
        *(ushort4*)(d)     = x.v;
        *(ushort4*)(d + 4) = y.v;
    }
};

// ---------------------------------------------------------------------------
// K0: convert six 128x128 fp32 weight matrices to bf16 in ws.
// (Proven: precomputed bf16 W beats inline fp32 cvt in proj_lr, 99.6 vs 108.)
// ---------------------------------------------------------------------------
__global__ __launch_bounds__(256) void cvt_w_kernel(
    const float* __restrict__ s0, const float* __restrict__ s1,
    const float* __restrict__ s2, const float* __restrict__ s3,
    const float* __restrict__ s4, const float* __restrict__ s5,
    bf16* __restrict__ dst)
{
    const float* srcs[6] = {s0, s1, s2, s3, s4, s5};
    const float* s = srcs[blockIdx.y];
    bf16* d = dst + blockIdx.y * (CC * CC);
    int i = (blockIdx.x * 256 + threadIdx.x) * 4;
    float4 f = *(const float4*)(s + i);
    union { ushort4 v; unsigned short u[4]; } p;
    p.u[0] = f2bfbits(f.x); p.u[1] = f2bfbits(f.y);
    p.u[2] = f2bfbits(f.z); p.u[3] = f2bfbits(f.w);
    *(ushort4*)(d + i) = p.v;
}

// ---------------------------------------------------------------------------
// K1: FUSED dual-sided projection (left AND right) — x read ONCE.
// R5-proven inner structure (99.6-113us, FETCH 68MB): 512 threads = 8
// waves, waves 0-3 left / 4-7 right; bf16 Wb fragments; post-barrier
// prefetch issue; commit after epilogue; rcp sigmoid.
// R13: T=4 -> 8 (grid 1024 -> 512): amortizes the exposed prologue (32
// W-frag loads/thread + uncovered tile-0 stage) over 2x work. Inner loop
// byte-identical — no sync/occupancy/traffic change.
// Ledger: LDS-staged fused 99.6-113; 256-split 106.6; inline-cvt 108;
// barrier-free 191. DO NOT restructure the staged-lockstep form.
// ---------------------------------------------------------------------------
__global__ __launch_bounds__(512, 2) void proj_lr_kernel(
    const float* __restrict__ X, const bf16* __restrict__ Wb,
    const float* __restrict__ Bl1, const float* __restrict__ Bl2,
    const float* __restrict__ Br1, const float* __restrict__ Br2,
    bf16* __restrict__ OUTL, bf16* __restrict__ OUTR)
{
    __shared__ bf16 xs[2][64][136];       // +8 bf16 pad: 272B row stride
    const int t = threadIdx.x;
    const int wave = t >> 6, lane = t & 63;
    const int grp = wave >> 2;            // 0 = left, 1 = right
    const int w4 = wave & 3;
    const int lrow = lane & 15, lq = lane >> 4;
    const int n0 = w4 * 32 + lrow;

    const bf16* W1 = Wb + (grp ? 2 * CC * CC : 0);
    const bf16* W2 = W1 + CC * CC;
    const float* B1 = grp ? Br1 : Bl1;
    const float* B2 = grp ? Br2 : Bl2;
    bf16* OUT = grp ? OUTR : OUTL;

    bf16x8 wf1[2][4], wf2[2][4];          // [nt_local][k0/32]
    float bias1[2], bias2[2];
    #pragma unroll
    for (int nl = 0; nl < 2; ++nl) {
        const int n = n0 + nl * 16;
        bias1[nl] = B1[n]; bias2[nl] = B2[n];
        #pragma unroll
        for (int kk = 0; kk < 4; ++kk) {
            wf1[nl][kk] = *(const bf16x8*)(W1 + n * CC + kk * 32 + lq * 8);
            wf2[nl][kk] = *(const bf16x8*)(W2 + n * CC + kk * 32 + lq * 8);
        }
    }

    constexpr int T = 8;
    const size_t block_row0 = (size_t)blockIdx.x * (64 * T);

    // stage tile 0 directly (8192 elements / 512 threads = 2 chunks of 8)
    #pragma unroll
    for (int it = 0; it < 2; ++it) {
        int chunk = it * 512 + t;
        int r = chunk >> 4, o = (chunk & 15) << 3;
        stage8(X + (block_row0 + r) * CC + o, &xs[0][r][o]);
    }

    #pragma unroll
    for (int tt = 0; tt < T; ++tt) {
        const size_t row0 = block_row0 + (size_t)tt * 64;
        const int cur = tt & 1;

        __syncthreads();   // xs[cur] staged; xs[cur^1] readers done

        // issue next tile's loads AFTER the barrier: they stay in flight
        // through MFMA + epilogue; vmcnt wait lands at commit() below.
        Raw8F pf[2];
        if (tt + 1 < T) {
            #pragma unroll
            for (int it = 0; it < 2; ++it) {
                int chunk = it * 512 + t;
                int r = chunk >> 4, o = (chunk & 15) << 3;
                pf[it].load(X + (row0 + 64 + r) * CC + o);
            }
        }

        f32x4 acc1[2][4], acc2[2][4];     // [nt_local][mt]
        const f32x4 z = {0.f, 0.f, 0.f, 0.f};
        #pragma unroll
        for (int nl = 0; nl < 2; ++nl)
            #pragma unroll
            for (int mt = 0; mt < 4; ++mt) { acc1[nl][mt] = z; acc2[nl][mt] = z; }

        #pragma unroll
        for (int kk = 0; kk < 4; ++kk) {
            bf16x8 a[4];
            #pragma unroll
            for (int mt = 0; mt < 4; ++mt)
                a[mt] = *(const bf16x8*)(&xs[cur][mt * 16 + lrow][kk * 32 + lq * 8]);
            #pragma unroll
            for (int nl = 0; nl < 2; ++nl)
                #pragma unroll
                for (int mt = 0; mt < 4; ++mt) {
                    acc1[nl][mt] = __builtin_amdgcn_mfma_f32_16x16x32_bf16(
                        a[mt], wf1[nl][kk], acc1[nl][mt], 0, 0, 0);
                    acc2[nl][mt] = __builtin_amdgcn_mfma_f32_16x16x32_bf16(
                        a[mt], wf2[nl][kk], acc2[nl][mt], 0, 0, 0);
                }
        }

        // epilogue: transposed bf16 store. C/D: col=lane&15 (n), row=lq*4+reg (m)
        #pragma unroll
        for (int nl = 0; nl < 2; ++nl) {
            const int n = n0 + nl * 16;
            #pragma unroll
            for (int mt = 0; mt < 4; ++mt) {
                const size_t m0 = row0 + mt * 16 + lq * 4;
                union { ushort4 v; unsigned short u[4]; } pk;
                #pragma unroll
                for (int r = 0; r < 4; ++r) {
                    float p1 = acc1[nl][mt][r] + bias1[nl];
                    float p2 = acc2[nl][mt][r] + bias2[nl];
                    pk.u[r] = f2bfbits(sig_gate(p1, p2));
                }
                *(ushort4*)(OUT + (size_t)n * MM + m0) = pk.v;
            }
        }

        // commit prefetched tile LAST: maximizes load-latency cover.
        if (tt + 1 < T) {
            #pragma unroll
            for (int it = 0; it < 2; ++it) {
                int chunk = it * 512 + t;
                int r = chunk >> 4, o = (chunk & 15) << 3;
                pf[it].commit(&xs[cur ^ 1][r][o]);
            }
        }
    }
}

// ---------------------------------------------------------------------------
// K2: per-channel batched GEMM  tri[c] = L_c (512x512) @ R_c^T (512x512)
// LOCKED round-0 structure — 90-99us, FETCH ~200MB, WRITE=ideal, VGPR 88,
// occupancy ~18% (proven rounds 0/2/5/6/7/9). DO NOT MODIFY the loop/grid:
// three pipelining attempts failed via (a) XCD-swizzle write concentration
// (R4: WRITE 3x), (b) 1-barrier desync read-reuse decay (R6: FETCH +45MB),
// (c) reg-prefetch occupancy rise -> L2 thrash (R7: WRITE 4x). The
// 2-barrier lockstep at ~5 blocks/CU IS the L2 locality mechanism.
// bf16 output (R9, verified: absmax unchanged at 0.03125).
// ---------------------------------------------------------------------------
template<typename TriT>
__global__ __launch_bounds__(256) void tri_mm_kernel(
    const bf16* __restrict__ Lt, const bf16* __restrict__ Rt,
    TriT* __restrict__ tri)
{
    __shared__ bf16 As[128][40];          // +8 bf16 pad: 80B row stride
    __shared__ bf16 Bs[128][40];
    const int c  = blockIdx.z;
    const int i0 = blockIdx.x * 128, j0 = blockIdx.y * 128;
    const bf16* Lb = Lt + (size_t)c * MM;
    const bf16* Rb = Rt + (size_t)c * MM;

    const int t    = threadIdx.x;
    const int wave = t >> 6, lane = t & 63;
    const int lrow = lane & 15, lq = lane >> 4;
    const int wi = (wave & 1) * 64, wj = (wave >> 1) * 64;

    f32x4 acc[4][4];
    const f32x4 z = {0.f, 0.f, 0.f, 0.f};
    #pragma unroll
    for (int mt = 0; mt < 4; ++mt)
        #pragma unroll
        for (int nt = 0; nt < 4; ++nt) acc[mt][nt] = z;

    for (int k0 = 0; k0 < LL; k0 += 32) {
        __syncthreads();
        #pragma unroll
        for (int it = 0; it < 2; ++it) {
            int chunk = it * 256 + t;
            int r = chunk >> 2, o = (chunk & 3) << 3;
            *(uint4*)(&As[r][o]) = *(const uint4*)(Lb + (size_t)(i0 + r) * LL + k0 + o);
            *(uint4*)(&Bs[r][o]) = *(const uint4*)(Rb + (size_t)(j0 + r) * LL + k0 + o);
        }
        __syncthreads();

        bf16x8 af[4], bfr[4];
        #pragma unroll
        for (int mt = 0; mt < 4; ++mt)
            af[mt] = *(const bf16x8*)(&As[wi + mt * 16 + lrow][lq * 8]);
        #pragma unroll
        for (int nt = 0; nt < 4; ++nt)
            bfr[nt] = *(const bf16x8*)(&Bs[wj + nt * 16 + lrow][lq * 8]);
        #pragma unroll
        for (int mt = 0; mt < 4; ++mt)
            #pragma unroll
            for (int nt = 0; nt < 4; ++nt)
                acc[mt][nt] = __builtin_amdgcn_mfma_f32_16x16x32_bf16(
                    af[mt], bfr[nt], acc[mt][nt], 0, 0, 0);
    }

    TriT* triC = tri + (size_t)c * MM;
    #pragma unroll
    for (int mt = 0; mt < 4; ++mt) {
        #pragma unroll
        for (int nt = 0; nt < 4; ++nt) {
            const int ib = i0 + wi + mt * 16 + lq * 4;
            const int j  = j0 + wj + nt * 16 + lrow;
            #pragma unroll
            for (int r = 0; r < 4; ++r)
                storeT(&triC[(size_t)(ib + r) * LL + j], acc[mt][nt][r]);
        }
    }
}

// ---------------------------------------------------------------------------
// K3: FUSED LayerNorm + output gating. (R6 inner structure; bf16 tri read;
// bf16 Wb weights.) R13: T=4 -> 8 — amortizes W-frag + tile-0 prologue.
// ---------------------------------------------------------------------------
template<typename TriT>
__global__ __launch_bounds__(256, 2) void ln_gate_kernel(
    const TriT* __restrict__ tri,
    const float* __restrict__ G, const float* __restrict__ Bt,
    const bf16* __restrict__ W1, const float* __restrict__ B1,
    const bf16* __restrict__ W2, const float* __restrict__ B2,
    float* __restrict__ OUT)
{
    __shared__ float s[128][68];          // tri tile [c][p], 272B row stride
    __shared__ bf16 xs[64][136];          // normalized bf16 tile [p][c]
    __shared__ float part[2][4][64];
    __shared__ float mu[64], rsd[64];
    __shared__ float gs[128], bs[128];

    const int t = threadIdx.x;
    const int wave = t >> 6, lane = t & 63;
    const int lrow = lane & 15, lq = lane >> 4;
    const int n0 = wave * 32 + lrow;

    if (t < 128) { gs[t] = G[t]; bs[t] = Bt[t]; }

    bf16x8 wf1[2][4], wf2[2][4];
    float bias1[2], bias2[2];
    #pragma unroll
    for (int nl = 0; nl < 2; ++nl) {
        const int n = n0 + nl * 16;
        bias1[nl] = B1[n]; bias2[nl] = B2[n];
        #pragma unroll
        for (int kk = 0; kk < 4; ++kk) {
            wf1[nl][kk] = *(const bf16x8*)(W1 + n * CC + kk * 32 + lq * 8);
            wf2[nl][kk] = *(const bf16x8*)(W2 + n * CC + kk * 32 + lq * 8);
        }
    }

    constexpr int T = 8;
    const size_t bp0 = (size_t)blockIdx.x * (64 * T);

    // prologue: stage tri tile 0 (128c x 64p -> s)
    #pragma unroll
    for (int it = 0; it < 8; ++it) {
        int idx = it * 256 + t;
        int cc = idx >> 4, p4 = (idx & 15) << 2;
        float4 f = load4(tri + (size_t)cc * MM + bp0 + p4);
        *(float4*)(&s[cc][p4]) = f;
    }

    for (int tt = 0; tt < T; ++tt) {
        const size_t p0 = bp0 + (size_t)tt * 64;

        float4 pf[8];
        if (tt + 1 < T) {
            #pragma unroll
            for (int it = 0; it < 8; ++it) {
                int idx = it * 256 + t;
                int cc = idx >> 4, p4 = (idx & 15) << 2;
                pf[it] = load4(tri + (size_t)cc * MM + p0 + 64 + p4);
            }
        }
        __syncthreads();   // (a) s staged (prologue or prev commit); gs/bs ready

        // LN stats: wave w sums channels [w*32, w*32+32) at position=lane
        float sum = 0.f, sq = 0.f;
        #pragma unroll 8
        for (int cc = wave * 32; cc < wave * 32 + 32; ++cc) {
            float v = s[cc][lane]; sum += v; sq += v * v;
        }
        part[0][wave][lane] = sum; part[1][wave][lane] = sq;
        __syncthreads();   // (b)
        if (t < 64) {
            float S = part[0][0][t] + part[0][1][t] + part[0][2][t] + part[0][3][t];
            float Q = part[1][0][t] + part[1][1][t] + part[1][2][t] + part[1][3][t];
            float m = S * (1.f / 128.f);
            float var = Q * (1.f / 128.f) - m * m;
            mu[t] = m; rsd[t] = rsqrtf(var + 1e-5f);
        }
        __syncthreads();   // (c)

        // normalize -> xs bf16. p = lane (conflict-free s reads), c8 uniform.
        #pragma unroll
        for (int it = 0; it < 4; ++it) {
            int chunk = it * 256 + t;
            int p = chunk & 63, c8 = (chunk >> 6) << 3;
            float m = mu[p], r = rsd[p];
            union { uint4 v; unsigned short u[8]; } pk;
            #pragma unroll
            for (int jj = 0; jj < 8; ++jj) {
                int cc = c8 + jj;
                pk.u[jj] = f2bfbits((s[cc][p] - m) * r * gs[cc] + bs[cc]);
            }
            *(uint4*)(&xs[p][c8]) = pk.v;
        }
        __syncthreads();   // (d) xs ready; all s reads done

        if (tt + 1 < T) {
            #pragma unroll
            for (int it = 0; it < 8; ++it) {
                int idx = it * 256 + t;
                int cc = idx >> 4, p4 = (idx & 15) << 2;
                *(float4*)(&s[cc][p4]) = pf[it];
            }
        }

        f32x4 acc1[2][4], acc2[2][4];
        const f32x4 z = {0.f, 0.f, 0.f, 0.f};
        #pragma unroll
        for (int nl = 0; nl < 2; ++nl)
            #pragma unroll
            for (int mt = 0; mt < 4; ++mt) { acc1[nl][mt] = z; acc2[nl][mt] = z; }

        #pragma unroll
        for (int kk = 0; kk < 4; ++kk) {
            bf16x8 a[4];
            #pragma unroll
            for (int mt = 0; mt < 4; ++mt)
                a[mt] = *(const bf16x8*)(&xs[mt * 16 + lrow][kk * 32 + lq * 8]);
            #pragma unroll
            for (int nl = 0; nl < 2; ++nl)
                #pragma unroll
                for (int mt = 0; mt < 4; ++mt) {
                    acc1[nl][mt] = __builtin_amdgcn_mfma_f32_16x16x32_bf16(
                        a[mt], wf1[nl][kk], acc1[nl][mt], 0, 0, 0);
                    acc2[nl][mt] = __builtin_amdgcn_mfma_f32_16x16x32_bf16(
                        a[mt], wf2[nl][kk], acc2[nl][mt], 0, 0, 0);
                }
        }

        // epilogue: fp32 out [M][128]
        #pragma unroll
        for (int nl = 0; nl < 2; ++nl) {
            const int n = n0 + nl * 16;
            #pragma unroll
            for (int mt = 0; mt < 4; ++mt) {
                const size_t m0 = p0 + mt * 16 + lq * 4;
                #pragma unroll
                for (int r = 0; r < 4; ++r) {
                    float p1 = acc1[nl][mt][r] + bias1[nl];
                    float p2 = acc2[nl][mt][r] + bias2[nl];
                    OUT[(m0 + r) * CC + n] = sig_gate(p1, p2);
                }
            }
        }
    }
}

// ---------------------------------------------------------------------------
extern "C" void kernel_launch(void* const* d_in, const int* in_sizes, int n_in,
                              void* d_out, int out_size, void* d_ws, size_t ws_size,
                              hipStream_t stream)
{
    const float* x   = (const float*)d_in[0];
    const float* Wl1 = (const float*)d_in[1];
    const float* bl1 = (const float*)d_in[2];
    const float* Wl2 = (const float*)d_in[3];
    const float* bl2 = (const float*)d_in[4];
    const float* Wr1 = (const float*)d_in[5];
    const float* br1 = (const float*)d_in[6];
    const float* Wr2 = (const float*)d_in[7];
    const float* br2 = (const float*)d_in[8];
    const float* Wg  = (const float*)d_in[9];
    const float* bg  = (const float*)d_in[10];
    const float* Wo  = (const float*)d_in[11];
    const float* bo  = (const float*)d_in[12];
    const float* lng = (const float*)d_in[13];
    const float* lnb = (const float*)d_in[14];
    float* out = (float*)d_out;

    char* ws = (char*)d_ws;
    bf16* left_t  = (bf16*)(ws);                        // 64 MiB bf16 [128][M]
    bf16* right_t = (bf16*)(ws + (64ull << 20));        // 64 MiB bf16 [128][M]
    bf16* Wb      = (bf16*)(ws + (128ull << 20));       // 192 KiB: 6 bf16 weights
    bf16* tri     = (bf16*)(ws + (132ull << 20));       // 64 MiB bf16 [128][M]

    bf16* Wbg = Wb + 4 * CC * CC;
    bf16* Wbo = Wb + 5 * CC * CC;

    dim3 blk(256);
    cvt_w_kernel<<<dim3(16, 6), blk, 0, stream>>>(Wl1, Wl2, Wr1, Wr2, Wg, Wo, Wb);
    proj_lr_kernel<<<dim3(MM / 512), dim3(512), 0, stream>>>(
        x, Wb, bl1, bl2, br1, br2, left_t, right_t);
    tri_mm_kernel<bf16><<<dim3(4, 4, 128), blk, 0, stream>>>(left_t, right_t, tri);
    ln_gate_kernel<bf16><<<dim3(MM / 512), blk, 0, stream>>>(
        tri, lng, lnb, Wbg, bg, Wbo, bo, out);
}